// Round 1
// baseline (1539.845 us; speedup 1.0000x reference)
//
#include <hip/hip_runtime.h>
#include <hip/hip_bf16.h>
#include <math.h>

// Pattern-aware MoE, MI355X. Sparse top-2 dispatch with bf16 MFMA grouped GEMMs.
// B=8 S=4096 D=512 H=2048 E=8 P=16 K=2.

#define B_ 8
#define S_ 4096
#define D_ 512
#define H_ 2048
#define E_ 8
#define P_ 16
#define NTOK (B_ * S_)      // 32768
#define NPAIR (NTOK * 2)    // 65536

typedef __bf16 bf16;
typedef __bf16 bf16x8 __attribute__((ext_vector_type(8)));
typedef float f32x4 __attribute__((ext_vector_type(4)));

// ---- workspace layout (bytes) ----
// 0   : counts[8]   (int)
// 32  : probSum[8]  (float)
// 64  : zSum        (float)
#define OFF_GATES 256
#define OFF_LIST (OFF_GATES + NPAIR * 4)
#define OFF_XBF (OFF_LIST + E_ * NTOK * 4)
#define OFF_W1T (OFF_XBF + (size_t)NTOK * D_ * 2)
#define OFF_W3T (OFF_W1T + (size_t)E_ * H_ * D_ * 2)
#define OFF_W2T (OFF_W3T + (size_t)E_ * H_ * D_ * 2)
#define OFF_HBUF (OFF_W2T + (size_t)E_ * D_ * H_ * 2)
#define WS_NEEDED (OFF_HBUF + (size_t)NTOK * H_ * 2)  // ~209 MiB

// ============================ router =====================================
// 1 block = 8 tokens (4 waves x 2). Computes logits (fp32), top-2 gates,
// list append, z/prob accumulators; also converts x rows to bf16.
__global__ __launch_bounds__(256) void router_kernel(
    const float* __restrict__ x, const int* __restrict__ pids,
    const float* __restrict__ Wr, const float* __restrict__ Wp,
    bf16* __restrict__ xbf, float* __restrict__ gates, int* __restrict__ lists,
    int* __restrict__ counts, float* __restrict__ probSum, float* __restrict__ zSum) {
  __shared__ float wr_s[E_][D_];  // transposed: [e][d] -> lane-stride-64 reads conflict-free
  __shared__ float wp_s[E_];
  __shared__ int slotE[16];
  __shared__ int slotP[16];
  __shared__ float probAcc[E_];
  __shared__ float zAcc;

  const int tid = threadIdx.x;
  const int tok0 = blockIdx.x * 8;

  for (int rep = 0; rep < 16; ++rep) {
    int flat = rep * 256 + tid;  // Wr is [D][E]
    wr_s[flat & 7][flat >> 3] = Wr[flat];
  }
  if (tid < E_) {
    int b = tok0 >> 12;  // S=4096 tokens per batch row, blocks never straddle b
    wp_s[tid] = Wp[pids[b] * E_ + tid];
    probAcc[tid] = 0.f;
  }
  if (tid == 0) zAcc = 0.f;
  __syncthreads();

  const int wave = tid >> 6, lane = tid & 63;
  for (int rep = 0; rep < 2; ++rep) {
    int t = tok0 + wave * 2 + rep;
    float acc[E_];
#pragma unroll
    for (int e = 0; e < E_; ++e) acc[e] = 0.f;
#pragma unroll
    for (int j = 0; j < 8; ++j) {
      int c = lane + 64 * j;
      float v = x[(size_t)t * D_ + c];
      xbf[(size_t)t * D_ + c] = (bf16)v;  // coalesced 2B stores
#pragma unroll
      for (int e = 0; e < E_; ++e) acc[e] += v * wr_s[e][c];
    }
#pragma unroll
    for (int off = 1; off < 64; off <<= 1) {
#pragma unroll
      for (int e = 0; e < E_; ++e) acc[e] += __shfl_xor(acc[e], off);
    }
    if (lane == 0) {
      float lg[E_];
#pragma unroll
      for (int e = 0; e < E_; ++e) lg[e] = acc[e] + wp_s[e];
      float m = lg[0];
#pragma unroll
      for (int e = 1; e < E_; ++e) m = fmaxf(m, lg[e]);
      float z = 0.f, s = 0.f, pe[E_];
#pragma unroll
      for (int e = 0; e < E_; ++e) {
        z += lg[e] * lg[e];
        pe[e] = expf(lg[e] - m);
        s += pe[e];
      }
      atomicAdd(&zAcc, z);
      float inv_s = 1.f / s;
#pragma unroll
      for (int e = 0; e < E_; ++e) atomicAdd(&probAcc[e], pe[e] * inv_s);
      // top-2, ties -> lower index first (matches jax.lax.top_k)
      int i1 = 0;
      float v1 = lg[0];
#pragma unroll
      for (int e = 1; e < E_; ++e)
        if (lg[e] > v1) { v1 = lg[e]; i1 = e; }
      int i2 = -1;
      float v2 = -1e30f;
#pragma unroll
      for (int e = 0; e < E_; ++e)
        if (e != i1 && lg[e] > v2) { v2 = lg[e]; i2 = e; }
      float ex = expf(v2 - v1);
      float g1 = 1.f / (1.f + ex);
      float g2 = ex / (1.f + ex);
      int pair0 = t * 2;
      gates[pair0] = g1;
      gates[pair0 + 1] = g2;
      int sb = wave * 4 + rep * 2;
      slotE[sb] = i1;
      slotP[sb] = pair0;
      slotE[sb + 1] = i2;
      slotP[sb + 1] = pair0 + 1;
    }
  }
  __syncthreads();
  if (tid < E_) {
    int cnt = 0;
#pragma unroll
    for (int s_ = 0; s_ < 16; ++s_) cnt += (slotE[s_] == tid) ? 1 : 0;
    if (cnt) {
      int base = atomicAdd(&counts[tid], cnt);
      int r = 0;
      for (int s_ = 0; s_ < 16; ++s_)
        if (slotE[s_] == tid) lists[tid * NTOK + base + (r++)] = slotP[s_];
    }
    atomicAdd(&probSum[tid], probAcc[tid]);
  } else if (tid == 8) {
    atomicAdd(zSum, zAcc);
  }
}

// ======================= transpose + fp32->bf16 ==========================
// in: fp32 [E][R][C]  ->  out: bf16 [E][C][R].  64x64 tiles; 2x2 micro-block
// packing keeps every LDS access >=4B and both global phases coalesced.
__global__ __launch_bounds__(256) void transpose_convert(const float* __restrict__ in,
                                                         bf16* __restrict__ out, int R, int C) {
  const int e = blockIdx.z;
  const int r0 = blockIdx.y * 64, c0 = blockIdx.x * 64;
  in += (size_t)e * R * C;
  out += (size_t)e * R * C;
  __shared__ unsigned int lt[64 * 33];  // [out_row(c)][row-pair dword], stride 33 (pad)

  const int tid = threadIdx.x;
  const int m = tid & 15, q = tid >> 4;  // m: col group, q: row-pair group (0..15)
#pragma unroll
  for (int rep = 0; rep < 2; ++rep) {
    int rp = q + rep * 16;  // row pair 0..31
    const float4 a = *(const float4*)(in + (size_t)(r0 + rp * 2) * C + c0 + m * 4);
    const float4 b = *(const float4*)(in + (size_t)(r0 + rp * 2 + 1) * C + c0 + m * 4);
#pragma unroll
    for (int j = 0; j < 4; ++j) {
      unsigned short lo = __builtin_bit_cast(unsigned short, (bf16)((&a.x)[j]));
      unsigned short hi = __builtin_bit_cast(unsigned short, (bf16)((&b.x)[j]));
      lt[(m * 4 + j) * 33 + rp] = (unsigned int)lo | ((unsigned int)hi << 16);
    }
  }
  __syncthreads();
  const int c = tid >> 2, dw0 = (tid & 3) * 8;
  unsigned int v[8];
#pragma unroll
  for (int j = 0; j < 8; ++j) v[j] = lt[c * 33 + dw0 + j];
  uint4* dst = (uint4*)(out + (size_t)(c0 + c) * R + r0 + dw0 * 2);
  dst[0] = make_uint4(v[0], v[1], v[2], v[3]);
  dst[1] = make_uint4(v[4], v[5], v[6], v[7]);
}

// ============================== GEMM1 ====================================
// Per expert e: H-act = gate * (X@W1e) * silu(X@W3e), rows gathered via list.
// Tile 128x128, BK=32, 4 waves of 64x64, dual accumulators share A tile.
__global__ __launch_bounds__(256) void gemm1_kernel(
    const bf16* __restrict__ xbf, const bf16* __restrict__ W1T, const bf16* __restrict__ W3T,
    const int* __restrict__ counts, const int* __restrict__ lists,
    const float* __restrict__ gates, bf16* __restrict__ hbuf, int e) {
  const int count = counts[e];
  const int m0 = blockIdx.y * 128;
  if (m0 >= count) return;
  const int n0 = blockIdx.x * 128;
  const int* list_e = lists + e * NTOK;
  const bf16* W1e = W1T + (size_t)e * H_ * D_;
  const bf16* W3e = W3T + (size_t)e * H_ * D_;

  __shared__ bf16 sA[128 * 32];
  __shared__ bf16 sB1[128 * 32];
  __shared__ bf16 sB3[128 * 32];
  __shared__ int stok[128];
  __shared__ float sgate[128];

  const int tid = threadIdx.x;
  if (tid < 128) {
    int rg = m0 + tid;
    int pr = (rg < count) ? list_e[rg] : 0;
    stok[tid] = pr >> 1;
    sgate[tid] = (rg < count) ? gates[pr] : 0.f;
  }
  __syncthreads();

  const int row = tid >> 1, half = tid & 1;
  const size_t aBase = (size_t)stok[row] * D_ + half * 16;
  const size_t bBase = (size_t)(n0 + row) * D_ + half * 16;

  const int wave = tid >> 6, lane = tid & 63;
  const int wm = wave >> 1, wn = wave & 1;
  const int lm = lane & 15, q = lane >> 4;

  f32x4 acc1[4][4] = {};
  f32x4 acc3[4][4] = {};

  bf16* sAw = sA + row * 32 + half * 16;
  bf16* sB1w = sB1 + row * 32 + half * 16;
  bf16* sB3w = sB3 + row * 32 + half * 16;
  const bf16* aRd = sA + (wm * 64 + lm) * 32 + q * 8;
  const bf16* b1Rd = sB1 + (wn * 64 + lm) * 32 + q * 8;
  const bf16* b3Rd = sB3 + (wn * 64 + lm) * 32 + q * 8;

  for (int k0 = 0; k0 < D_; k0 += 32) {
    uint4 av0 = *(const uint4*)(xbf + aBase + k0);
    uint4 av1 = *(const uint4*)(xbf + aBase + k0 + 8);
    uint4 b1v0 = *(const uint4*)(W1e + bBase + k0);
    uint4 b1v1 = *(const uint4*)(W1e + bBase + k0 + 8);
    uint4 b3v0 = *(const uint4*)(W3e + bBase + k0);
    uint4 b3v1 = *(const uint4*)(W3e + bBase + k0 + 8);
    __syncthreads();
    *(uint4*)(sAw) = av0;
    *(uint4*)(sAw + 8) = av1;
    *(uint4*)(sB1w) = b1v0;
    *(uint4*)(sB1w + 8) = b1v1;
    *(uint4*)(sB3w) = b3v0;
    *(uint4*)(sB3w + 8) = b3v1;
    __syncthreads();
    bf16x8 af[4], b1f[4], b3f[4];
#pragma unroll
    for (int i = 0; i < 4; ++i) {
      af[i] = *(const bf16x8*)(aRd + i * 16 * 32);
      b1f[i] = *(const bf16x8*)(b1Rd + i * 16 * 32);
      b3f[i] = *(const bf16x8*)(b3Rd + i * 16 * 32);
    }
#pragma unroll
    for (int mt = 0; mt < 4; ++mt) {
#pragma unroll
      for (int nt = 0; nt < 4; ++nt) {
        acc1[mt][nt] =
            __builtin_amdgcn_mfma_f32_16x16x32_bf16(af[mt], b1f[nt], acc1[mt][nt], 0, 0, 0);
        acc3[mt][nt] =
            __builtin_amdgcn_mfma_f32_16x16x32_bf16(af[mt], b3f[nt], acc3[mt][nt], 0, 0, 0);
      }
    }
  }

#pragma unroll
  for (int mt = 0; mt < 4; ++mt) {
#pragma unroll
    for (int nt = 0; nt < 4; ++nt) {
#pragma unroll
      for (int r = 0; r < 4; ++r) {
        int lrow = wm * 64 + mt * 16 + q * 4 + r;  // C/D: row=(lane>>4)*4+reg, col=lane&15
        int grow = m0 + lrow;
        if (grow < count) {
          float v1 = acc1[mt][nt][r];
          float v3 = acc3[mt][nt][r];
          float g = v1 * (v3 / (1.f + __expf(-v3))) * sgate[lrow];
          hbuf[(size_t)grow * H_ + n0 + wn * 64 + nt * 16 + lm] = (bf16)g;
        }
      }
    }
  }
}

// ============================== GEMM2 ====================================
// y += hact @ W2e (gate already folded into hact rows); scatter by atomicAdd.
__global__ __launch_bounds__(256) void gemm2_kernel(const bf16* __restrict__ hbuf,
                                                    const bf16* __restrict__ W2T,
                                                    const int* __restrict__ counts,
                                                    const int* __restrict__ lists,
                                                    float* __restrict__ y, int e) {
  const int count = counts[e];
  const int m0 = blockIdx.y * 128;
  if (m0 >= count) return;
  const int n0 = blockIdx.x * 128;
  const bf16* W2e = W2T + (size_t)e * D_ * H_;
  const int* list_e = lists + e * NTOK;

  __shared__ bf16 sA[128 * 32];
  __shared__ bf16 sB[128 * 32];
  __shared__ int stok[128];

  const int tid = threadIdx.x;
  if (tid < 128) {
    int rg = m0 + tid;
    stok[tid] = (rg < count) ? (list_e[rg] >> 1) : 0;
  }
  __syncthreads();

  const int row = tid >> 1, half = tid & 1;
  const size_t aBase = (size_t)(m0 + row) * H_ + half * 16;
  const size_t bBase = (size_t)(n0 + row) * H_ + half * 16;

  const int wave = tid >> 6, lane = tid & 63;
  const int wm = wave >> 1, wn = wave & 1;
  const int lm = lane & 15, q = lane >> 4;

  f32x4 acc[4][4] = {};

  bf16* sAw = sA + row * 32 + half * 16;
  bf16* sBw = sB + row * 32 + half * 16;
  const bf16* aRd = sA + (wm * 64 + lm) * 32 + q * 8;
  const bf16* bRd = sB + (wn * 64 + lm) * 32 + q * 8;

  for (int k0 = 0; k0 < H_; k0 += 32) {
    uint4 av0 = *(const uint4*)(hbuf + aBase + k0);
    uint4 av1 = *(const uint4*)(hbuf + aBase + k0 + 8);
    uint4 bv0 = *(const uint4*)(W2e + bBase + k0);
    uint4 bv1 = *(const uint4*)(W2e + bBase + k0 + 8);
    __syncthreads();
    *(uint4*)(sAw) = av0;
    *(uint4*)(sAw + 8) = av1;
    *(uint4*)(sBw) = bv0;
    *(uint4*)(sBw + 8) = bv1;
    __syncthreads();
    bf16x8 af[4], bf_[4];
#pragma unroll
    for (int i = 0; i < 4; ++i) {
      af[i] = *(const bf16x8*)(aRd + i * 16 * 32);
      bf_[i] = *(const bf16x8*)(bRd + i * 16 * 32);
    }
#pragma unroll
    for (int mt = 0; mt < 4; ++mt) {
#pragma unroll
      for (int nt = 0; nt < 4; ++nt) {
        acc[mt][nt] =
            __builtin_amdgcn_mfma_f32_16x16x32_bf16(af[mt], bf_[nt], acc[mt][nt], 0, 0, 0);
      }
    }
  }

#pragma unroll
  for (int mt = 0; mt < 4; ++mt) {
#pragma unroll
    for (int nt = 0; nt < 4; ++nt) {
#pragma unroll
      for (int r = 0; r < 4; ++r) {
        int lrow = wm * 64 + mt * 16 + q * 4 + r;
        int grow = m0 + lrow;
        if (grow < count) {
          atomicAdd(&y[(size_t)stok[lrow] * D_ + n0 + wn * 64 + nt * 16 + lm], acc[mt][nt][r]);
        }
      }
    }
  }
}

// ============================= finalize ==================================
__global__ __launch_bounds__(256) void finalize_kernel(const float* __restrict__ Wp,
                                                       const float* __restrict__ probSum,
                                                       const float* __restrict__ zSum,
                                                       float* __restrict__ out) {
  __shared__ float pn[P_][E_];
  __shared__ float simAcc;
  const int tid = threadIdx.x;
  if (tid == 0) simAcc = 0.f;
  if (tid < P_) {
    float v[E_], m = -1e30f, s = 0.f;
#pragma unroll
    for (int e = 0; e < E_; ++e) {
      v[e] = Wp[tid * E_ + e];
      m = fmaxf(m, v[e]);
    }
#pragma unroll
    for (int e = 0; e < E_; ++e) {
      float ex = expf(v[e] - m);
      pn[tid][e] = ex;
      s += ex;
    }
#pragma unroll
    for (int e = 0; e < E_; ++e) pn[tid][e] /= s;
  }
  __syncthreads();
  {
    int i = tid >> 4, j = tid & 15;
    if (i != j) {
      float d = 0.f;
#pragma unroll
      for (int e = 0; e < E_; ++e) d += pn[i][e] * pn[j][e];
      atomicAdd(&simAcc, d);
    }
  }
  __syncthreads();
  if (tid == 0) {
    out[0] = zSum[0] / (float)(NTOK * E_) * 0.001f;
    float bl = 0.f;
#pragma unroll
    for (int e = 0; e < E_; ++e) {
      float pm = probSum[e] / (float)NTOK - 1.f / (float)E_;
      bl += pm * pm;
    }
    out[1] = bl / (float)E_;
    out[2] = simAcc / (float)(P_ * P_) * 0.1f;
  }
}

// ============================== launch ===================================
extern "C" void kernel_launch(void* const* d_in, const int* in_sizes, int n_in, void* d_out,
                              int out_size, void* d_ws, size_t ws_size, hipStream_t stream) {
  const float* x = (const float*)d_in[0];
  const int* pids = (const int*)d_in[1];
  const float* Wr = (const float*)d_in[2];
  const float* Wp = (const float*)d_in[3];
  const float* W1 = (const float*)d_in[4];
  const float* W2 = (const float*)d_in[5];
  const float* W3 = (const float*)d_in[6];
  float* y = (float*)d_out;

  if (ws_size < WS_NEEDED) return;  // fail loudly (poison output) rather than corrupt

  char* ws = (char*)d_ws;
  int* counts = (int*)ws;
  float* probSum = (float*)(ws + 32);
  float* zSum = (float*)(ws + 64);
  float* gates = (float*)(ws + OFF_GATES);
  int* lists = (int*)(ws + OFF_LIST);
  bf16* xbf = (bf16*)(ws + OFF_XBF);
  bf16* W1T = (bf16*)(ws + OFF_W1T);
  bf16* W3T = (bf16*)(ws + OFF_W3T);
  bf16* W2T = (bf16*)(ws + OFF_W2T);
  bf16* hbuf = (bf16*)(ws + OFF_HBUF);

  hipMemsetAsync(ws, 0, 256, stream);                           // counts + loss accumulators
  hipMemsetAsync(d_out, 0, (size_t)NTOK * D_ * 4, stream);      // y base for atomic combine

  router_kernel<<<dim3(NTOK / 8), 256, 0, stream>>>(x, pids, Wr, Wp, xbf, gates, lists, counts,
                                                    probSum, zSum);
  transpose_convert<<<dim3(H_ / 64, D_ / 64, E_), 256, 0, stream>>>(W1, W1T, D_, H_);
  transpose_convert<<<dim3(H_ / 64, D_ / 64, E_), 256, 0, stream>>>(W3, W3T, D_, H_);
  transpose_convert<<<dim3(D_ / 64, H_ / 64, E_), 256, 0, stream>>>(W2, W2T, H_, D_);

  for (int e = 0; e < E_; ++e) {
    gemm1_kernel<<<dim3(H_ / 128, NTOK / 128), 256, 0, stream>>>(xbf, W1T, W3T, counts, lists,
                                                                 gates, hbuf, e);
    gemm2_kernel<<<dim3(D_ / 128, NTOK / 128), 256, 0, stream>>>(hbuf, W2T, counts, lists, y, e);
  }
  finalize_kernel<<<1, 256, 0, stream>>>(Wp, probSum, zSum, y + (size_t)NTOK * D_);
}

// Round 2
// 1445.178 us; speedup vs baseline: 1.0655x; 1.0655x over previous
//
#include <hip/hip_runtime.h>
#include <hip/hip_bf16.h>
#include <math.h>

// Pattern-aware MoE, MI355X. Sparse top-2 dispatch with bf16 MFMA grouped GEMMs.
// B=8 S=4096 D=512 H=2048 E=8 P=16 K=2.
// R2: pair-per-lane router (no butterflies, Wr staged once per 32 tokens),
//     global_load_lds width-16 staging in both GEMMs (m97 structure).

#define B_ 8
#define S_ 4096
#define D_ 512
#define H_ 2048
#define E_ 8
#define P_ 16
#define NTOK (B_ * S_)      // 32768
#define NPAIR (NTOK * 2)    // 65536

typedef __bf16 bf16;
typedef __bf16 bf16x8 __attribute__((ext_vector_type(8)));
typedef float f32x4 __attribute__((ext_vector_type(4)));

// ---- workspace layout (bytes) ----
#define OFF_GATES 256
#define OFF_LIST (OFF_GATES + NPAIR * 4)
#define OFF_XBF (OFF_LIST + E_ * NTOK * 4)
#define OFF_W1T (OFF_XBF + (size_t)NTOK * D_ * 2)
#define OFF_W3T (OFF_W1T + (size_t)E_ * H_ * D_ * 2)
#define OFF_W2T (OFF_W3T + (size_t)E_ * H_ * D_ * 2)
#define OFF_HBUF (OFF_W2T + (size_t)E_ * D_ * H_ * 2)
#define WS_NEEDED (OFF_HBUF + (size_t)NTOK * H_ * 2)  // ~209 MiB

// async global->LDS, 16B per lane; LDS dest = base + lane*16 (wave-uniform base)
__device__ __forceinline__ void gl16(const bf16* g, bf16* l) {
  __builtin_amdgcn_global_load_lds((const __attribute__((address_space(1))) unsigned int*)g,
                                   (__attribute__((address_space(3))) unsigned int*)l, 16, 0, 0);
}

// ============================ router =====================================
// 1 block = 32 tokens, 256 threads. Phase1: stage x (fp32, padded) + Wr^T in
// LDS, emit xbf. Phase2: lane=(token,expert) computes one logit (conflict-free
// float4 LDS reads). Phase3: per-octet top-2/softmax, shuffle-reduced stats.
__global__ __launch_bounds__(256) void router_kernel(
    const float* __restrict__ x, const int* __restrict__ pids,
    const float* __restrict__ Wr, const float* __restrict__ Wp,
    bf16* __restrict__ xbf, float* __restrict__ gates, int* __restrict__ lists,
    int* __restrict__ counts, float* __restrict__ probSum, float* __restrict__ zSum) {
  __shared__ float xs[32 * 516];     // stride 516: 8 rows/wave land on distinct banks
  __shared__ float wr_s[E_ * 516];   // [e][d], stride 516
  __shared__ float wp_s[E_];
  __shared__ float probAcc[E_];
  __shared__ float zAcc;
  __shared__ int lcnt[E_], lbase[E_];
  __shared__ float lg_s[32][E_ + 1];

  const int tid = threadIdx.x;
  const int tok0 = blockIdx.x * 32;

  // Wr is [D][E] -> wr_s[e*516 + d]
#pragma unroll
  for (int rep = 0; rep < (D_ * E_) / 256; ++rep) {
    int flat = rep * 256 + tid;
    wr_s[(flat & 7) * 516 + (flat >> 3)] = Wr[flat];
  }
  if (tid < E_) {
    wp_s[tid] = Wp[pids[tok0 >> 12] * E_ + tid];  // blocks never straddle batch rows
    probAcc[tid] = 0.f;
    lcnt[tid] = 0;
  }
  if (tid == 0) zAcc = 0.f;

  // stage x tile + write bf16 copy (both coalesced)
  const float4* x4 = (const float4*)(x + (size_t)tok0 * D_);
#pragma unroll
  for (int rep = 0; rep < 16; ++rep) {
    int idx = rep * 256 + tid;  // float4 index in 32x512 tile
    float4 v = x4[idx];
    int t = idx >> 7;           // 128 float4 per row
    int d = (idx & 127) * 4;
    *(float4*)(xs + t * 516 + d) = v;
    union { unsigned short u[4]; uint2 qq; } pk;
    pk.u[0] = __builtin_bit_cast(unsigned short, (bf16)v.x);
    pk.u[1] = __builtin_bit_cast(unsigned short, (bf16)v.y);
    pk.u[2] = __builtin_bit_cast(unsigned short, (bf16)v.z);
    pk.u[3] = __builtin_bit_cast(unsigned short, (bf16)v.w);
    *(uint2*)(xbf + (size_t)tok0 * D_ + (size_t)idx * 4) = pk.qq;
  }
  __syncthreads();

  const int t = tid >> 3, e = tid & 7;
  const int lane = tid & 63;
  {
    float a0 = 0.f, a1 = 0.f, a2 = 0.f, a3 = 0.f;
    const float* xr = xs + t * 516;
    const float* wr = wr_s + e * 516;
#pragma unroll 8
    for (int d = 0; d < D_; d += 4) {
      float4 xv = *(const float4*)(xr + d);
      float4 wv = *(const float4*)(wr + d);
      a0 += xv.x * wv.x;
      a1 += xv.y * wv.y;
      a2 += xv.z * wv.z;
      a3 += xv.w * wv.w;
    }
    lg_s[t][e] = (a0 + a1) + (a2 + a3) + wp_s[e];
  }
  __syncthreads();

  float v[E_];
#pragma unroll
  for (int k = 0; k < E_; ++k) v[k] = lg_s[t][k];
  const float lg = v[e];
  float m = v[0];
#pragma unroll
  for (int k = 1; k < E_; ++k) m = fmaxf(m, v[k]);
  float s = 0.f;
#pragma unroll
  for (int k = 0; k < E_; ++k) s += expf(v[k] - m);
  float prob = expf(lg - m) / s;
  float z = lg * lg;
  // top-2 (ties -> lower index, matching lax.top_k)
  int i1 = 0;
  float v1 = v[0];
#pragma unroll
  for (int k = 1; k < E_; ++k)
    if (v[k] > v1) { v1 = v[k]; i1 = k; }
  int i2 = -1;
  float v2 = -1e30f;
#pragma unroll
  for (int k = 0; k < E_; ++k)
    if (k != i1 && v[k] > v2) { v2 = v[k]; i2 = k; }

  // stats reductions: same-e lanes are stride-8 within the wave
  float p = prob;
  p += __shfl_xor(p, 8);
  p += __shfl_xor(p, 16);
  p += __shfl_xor(p, 32);
  float zz = z;
#pragma unroll
  for (int off = 1; off < 64; off <<= 1) zz += __shfl_xor(zz, off);
  if (lane < 8) atomicAdd(&probAcc[e], p);
  if (lane == 0) atomicAdd(&zAcc, zz);

  // selection + local list append
  int r = (e == i1) ? 0 : ((e == i2) ? 1 : -1);
  int pos = -1;
  if (r >= 0) {
    float ex = expf(v2 - v1);
    float g = (r == 0) ? 1.f / (1.f + ex) : ex / (1.f + ex);
    gates[(tok0 + t) * 2 + r] = g;
    pos = atomicAdd(&lcnt[e], 1);
  }
  __syncthreads();
  if (tid < E_) lbase[tid] = atomicAdd(&counts[tid], lcnt[tid]);
  __syncthreads();
  if (r >= 0) lists[e * NTOK + lbase[e] + pos] = (tok0 + t) * 2 + r;
  if (tid < E_) atomicAdd(&probSum[tid], probAcc[tid]);
  else if (tid == 8) atomicAdd(zSum, zAcc);
}

// ======================= transpose + fp32->bf16 ==========================
__global__ __launch_bounds__(256) void transpose_convert(const float* __restrict__ in,
                                                         bf16* __restrict__ out, int R, int C) {
  const int e = blockIdx.z;
  const int r0 = blockIdx.y * 64, c0 = blockIdx.x * 64;
  in += (size_t)e * R * C;
  out += (size_t)e * R * C;
  __shared__ unsigned int lt[64 * 33];

  const int tid = threadIdx.x;
  const int m = tid & 15, q = tid >> 4;
#pragma unroll
  for (int rep = 0; rep < 2; ++rep) {
    int rp = q + rep * 16;
    const float4 a = *(const float4*)(in + (size_t)(r0 + rp * 2) * C + c0 + m * 4);
    const float4 b = *(const float4*)(in + (size_t)(r0 + rp * 2 + 1) * C + c0 + m * 4);
#pragma unroll
    for (int j = 0; j < 4; ++j) {
      unsigned short lo = __builtin_bit_cast(unsigned short, (bf16)((&a.x)[j]));
      unsigned short hi = __builtin_bit_cast(unsigned short, (bf16)((&b.x)[j]));
      lt[(m * 4 + j) * 33 + rp] = (unsigned int)lo | ((unsigned int)hi << 16);
    }
  }
  __syncthreads();
  const int c = tid >> 2, dw0 = (tid & 3) * 8;
  unsigned int vv[8];
#pragma unroll
  for (int j = 0; j < 8; ++j) vv[j] = lt[c * 33 + dw0 + j];
  uint4* dst = (uint4*)(out + (size_t)(c0 + c) * R + r0 + dw0 * 2);
  dst[0] = make_uint4(vv[0], vv[1], vv[2], vv[3]);
  dst[1] = make_uint4(vv[4], vv[5], vv[6], vv[7]);
}

// ============================== GEMM1 ====================================
// h = gate * (X@W1e) * silu(X@W3e); 128x128 tile, BK=32, global_load_lds.
__global__ __launch_bounds__(256) void gemm1_kernel(
    const bf16* __restrict__ xbf, const bf16* __restrict__ W1T, const bf16* __restrict__ W3T,
    const int* __restrict__ counts, const int* __restrict__ lists,
    const float* __restrict__ gates, bf16* __restrict__ hbuf, int e) {
  const int count = counts[e];
  const int m0 = blockIdx.y * 128;
  if (m0 >= count) return;
  const int n0 = blockIdx.x * 128;
  const int* list_e = lists + e * NTOK;
  const bf16* W1e = W1T + (size_t)e * H_ * D_;
  const bf16* W3e = W3T + (size_t)e * H_ * D_;

  __shared__ bf16 sA[128 * 32];
  __shared__ bf16 sB1[128 * 32];
  __shared__ bf16 sB3[128 * 32];
  __shared__ int stok[128];
  __shared__ float sgate[128];

  const int tid = threadIdx.x;
  if (tid < 128) {
    int rg = m0 + tid;
    int pr = (rg < count) ? list_e[rg] : 0;
    stok[tid] = pr >> 1;
    sgate[tid] = (rg < count) ? gates[pr] : 0.f;
  }
  __syncthreads();

  const int wave = tid >> 6, lane = tid & 63;
  // staging map: LDS chunk = row*4 + kq; instr j covers rows [16j,16j+16)
  const int rsub = lane >> 2, kq = lane & 3;
  const int rA0 = wave * 16 + rsub, rA1 = 64 + wave * 16 + rsub;
  const bf16* aP0 = xbf + (size_t)stok[rA0] * D_ + kq * 8;
  const bf16* aP1 = xbf + (size_t)stok[rA1] * D_ + kq * 8;
  const bf16* b1P0 = W1e + (size_t)(n0 + rA0) * D_ + kq * 8;
  const bf16* b1P1 = W1e + (size_t)(n0 + rA1) * D_ + kq * 8;
  const bf16* b3P0 = W3e + (size_t)(n0 + rA0) * D_ + kq * 8;
  const bf16* b3P1 = W3e + (size_t)(n0 + rA1) * D_ + kq * 8;
  bf16* lA0 = sA + wave * 512;
  bf16* lA1 = sA + (wave + 4) * 512;
  bf16* lB10 = sB1 + wave * 512;
  bf16* lB11 = sB1 + (wave + 4) * 512;
  bf16* lB30 = sB3 + wave * 512;
  bf16* lB31 = sB3 + (wave + 4) * 512;

  const int wm = wave >> 1, wn = wave & 1;
  const int lm = lane & 15, q = lane >> 4;
  const bf16* aRd = sA + (wm * 64 + lm) * 32 + q * 8;
  const bf16* b1Rd = sB1 + (wn * 64 + lm) * 32 + q * 8;
  const bf16* b3Rd = sB3 + (wn * 64 + lm) * 32 + q * 8;

  f32x4 acc1[4][4] = {};
  f32x4 acc3[4][4] = {};

  for (int k0 = 0; k0 < D_; k0 += 32) {
    __syncthreads();  // prior tile fully consumed
    gl16(aP0 + k0, lA0);
    gl16(aP1 + k0, lA1);
    gl16(b1P0 + k0, lB10);
    gl16(b1P1 + k0, lB11);
    gl16(b3P0 + k0, lB30);
    gl16(b3P1 + k0, lB31);
    __syncthreads();  // vmcnt(0) drain -> tile visible
    bf16x8 af[4], b1f[4], b3f[4];
#pragma unroll
    for (int i = 0; i < 4; ++i) {
      af[i] = *(const bf16x8*)(aRd + i * 16 * 32);
      b1f[i] = *(const bf16x8*)(b1Rd + i * 16 * 32);
      b3f[i] = *(const bf16x8*)(b3Rd + i * 16 * 32);
    }
#pragma unroll
    for (int mt = 0; mt < 4; ++mt) {
#pragma unroll
      for (int nt = 0; nt < 4; ++nt) {
        acc1[mt][nt] =
            __builtin_amdgcn_mfma_f32_16x16x32_bf16(af[mt], b1f[nt], acc1[mt][nt], 0, 0, 0);
        acc3[mt][nt] =
            __builtin_amdgcn_mfma_f32_16x16x32_bf16(af[mt], b3f[nt], acc3[mt][nt], 0, 0, 0);
      }
    }
  }

#pragma unroll
  for (int mt = 0; mt < 4; ++mt) {
#pragma unroll
    for (int nt = 0; nt < 4; ++nt) {
#pragma unroll
      for (int r = 0; r < 4; ++r) {
        int lrow = wm * 64 + mt * 16 + q * 4 + r;  // C/D: row=(lane>>4)*4+reg, col=lane&15
        int grow = m0 + lrow;
        if (grow < count) {
          float v1 = acc1[mt][nt][r];
          float v3 = acc3[mt][nt][r];
          float g = v1 * (v3 / (1.f + __expf(-v3))) * sgate[lrow];
          hbuf[(size_t)grow * H_ + n0 + wn * 64 + nt * 16 + lm] = (bf16)g;
        }
      }
    }
  }
}

// ============================== GEMM2 ====================================
// y += hact @ W2e^T rows; scatter via atomicAdd (exactly 2 contribs/token).
__global__ __launch_bounds__(256) void gemm2_kernel(const bf16* __restrict__ hbuf,
                                                    const bf16* __restrict__ W2T,
                                                    const int* __restrict__ counts,
                                                    const int* __restrict__ lists,
                                                    float* __restrict__ y, int e) {
  const int count = counts[e];
  const int m0 = blockIdx.y * 128;
  if (m0 >= count) return;
  const int n0 = blockIdx.x * 128;
  const bf16* W2e = W2T + (size_t)e * D_ * H_;
  const int* list_e = lists + e * NTOK;

  __shared__ bf16 sA[128 * 32];
  __shared__ bf16 sB[128 * 32];
  __shared__ int stok[128];

  const int tid = threadIdx.x;
  if (tid < 128) {
    int rg = m0 + tid;
    stok[tid] = (rg < count) ? (list_e[rg] >> 1) : 0;
  }
  __syncthreads();

  const int wave = tid >> 6, lane = tid & 63;
  const int rsub = lane >> 2, kq = lane & 3;
  const int rA0 = wave * 16 + rsub, rA1 = 64 + wave * 16 + rsub;
  const bf16* aP0 = hbuf + (size_t)(m0 + rA0) * H_ + kq * 8;
  const bf16* aP1 = hbuf + (size_t)(m0 + rA1) * H_ + kq * 8;
  const bf16* bP0 = W2e + (size_t)(n0 + rA0) * H_ + kq * 8;
  const bf16* bP1 = W2e + (size_t)(n0 + rA1) * H_ + kq * 8;
  bf16* lA0 = sA + wave * 512;
  bf16* lA1 = sA + (wave + 4) * 512;
  bf16* lB0 = sB + wave * 512;
  bf16* lB1 = sB + (wave + 4) * 512;

  const int wm = wave >> 1, wn = wave & 1;
  const int lm = lane & 15, q = lane >> 4;
  const bf16* aRd = sA + (wm * 64 + lm) * 32 + q * 8;
  const bf16* bRd = sB + (wn * 64 + lm) * 32 + q * 8;

  f32x4 acc[4][4] = {};

  for (int k0 = 0; k0 < H_; k0 += 32) {
    __syncthreads();
    gl16(aP0 + k0, lA0);
    gl16(aP1 + k0, lA1);
    gl16(bP0 + k0, lB0);
    gl16(bP1 + k0, lB1);
    __syncthreads();
    bf16x8 af[4], bf_[4];
#pragma unroll
    for (int i = 0; i < 4; ++i) {
      af[i] = *(const bf16x8*)(aRd + i * 16 * 32);
      bf_[i] = *(const bf16x8*)(bRd + i * 16 * 32);
    }
#pragma unroll
    for (int mt = 0; mt < 4; ++mt) {
#pragma unroll
      for (int nt = 0; nt < 4; ++nt) {
        acc[mt][nt] =
            __builtin_amdgcn_mfma_f32_16x16x32_bf16(af[mt], bf_[nt], acc[mt][nt], 0, 0, 0);
      }
    }
  }

#pragma unroll
  for (int mt = 0; mt < 4; ++mt) {
#pragma unroll
    for (int nt = 0; nt < 4; ++nt) {
#pragma unroll
      for (int r = 0; r < 4; ++r) {
        int lrow = wm * 64 + mt * 16 + q * 4 + r;
        int grow = m0 + lrow;
        if (grow < count) {
          atomicAdd(&y[(size_t)stok[lrow] * D_ + n0 + wn * 64 + nt * 16 + lm], acc[mt][nt][r]);
        }
      }
    }
  }
}

// ============================= finalize ==================================
__global__ __launch_bounds__(256) void finalize_kernel(const float* __restrict__ Wp,
                                                       const float* __restrict__ probSum,
                                                       const float* __restrict__ zSum,
                                                       float* __restrict__ out) {
  __shared__ float pn[P_][E_];
  __shared__ float simAcc;
  const int tid = threadIdx.x;
  if (tid == 0) simAcc = 0.f;
  if (tid < P_) {
    float v[E_], m = -1e30f, s = 0.f;
#pragma unroll
    for (int e = 0; e < E_; ++e) {
      v[e] = Wp[tid * E_ + e];
      m = fmaxf(m, v[e]);
    }
#pragma unroll
    for (int e = 0; e < E_; ++e) {
      float ex = expf(v[e] - m);
      pn[tid][e] = ex;
      s += ex;
    }
#pragma unroll
    for (int e = 0; e < E_; ++e) pn[tid][e] /= s;
  }
  __syncthreads();
  {
    int i = tid >> 4, j = tid & 15;
    if (i != j) {
      float d = 0.f;
#pragma unroll
      for (int e = 0; e < E_; ++e) d += pn[i][e] * pn[j][e];
      atomicAdd(&simAcc, d);
    }
  }
  __syncthreads();
  if (tid == 0) {
    out[0] = zSum[0] / (float)(NTOK * E_) * 0.001f;
    float bl = 0.f;
#pragma unroll
    for (int e = 0; e < E_; ++e) {
      float pm = probSum[e] / (float)NTOK - 1.f / (float)E_;
      bl += pm * pm;
    }
    out[1] = bl / (float)E_;
    out[2] = simAcc / (float)(P_ * P_) * 0.1f;
  }
}

// ============================== launch ===================================
extern "C" void kernel_launch(void* const* d_in, const int* in_sizes, int n_in, void* d_out,
                              int out_size, void* d_ws, size_t ws_size, hipStream_t stream) {
  const float* x = (const float*)d_in[0];
  const int* pids = (const int*)d_in[1];
  const float* Wr = (const float*)d_in[2];
  const float* Wp = (const float*)d_in[3];
  const float* W1 = (const float*)d_in[4];
  const float* W2 = (const float*)d_in[5];
  const float* W3 = (const float*)d_in[6];
  float* y = (float*)d_out;

  if (ws_size < WS_NEEDED) return;

  char* ws = (char*)d_ws;
  int* counts = (int*)ws;
  float* probSum = (float*)(ws + 32);
  float* zSum = (float*)(ws + 64);
  float* gates = (float*)(ws + OFF_GATES);
  int* lists = (int*)(ws + OFF_LIST);
  bf16* xbf = (bf16*)(ws + OFF_XBF);
  bf16* W1T = (bf16*)(ws + OFF_W1T);
  bf16* W3T = (bf16*)(ws + OFF_W3T);
  bf16* W2T = (bf16*)(ws + OFF_W2T);
  bf16* hbuf = (bf16*)(ws + OFF_HBUF);

  hipMemsetAsync(ws, 0, 256, stream);
  hipMemsetAsync(d_out, 0, (size_t)NTOK * D_ * 4, stream);

  router_kernel<<<dim3(NTOK / 32), 256, 0, stream>>>(x, pids, Wr, Wp, xbf, gates, lists, counts,
                                                     probSum, zSum);
  transpose_convert<<<dim3(H_ / 64, D_ / 64, E_), 256, 0, stream>>>(W1, W1T, D_, H_);
  transpose_convert<<<dim3(H_ / 64, D_ / 64, E_), 256, 0, stream>>>(W3, W3T, D_, H_);
  transpose_convert<<<dim3(D_ / 64, H_ / 64, E_), 256, 0, stream>>>(W2, W2T, H_, D_);

  for (int e = 0; e < E_; ++e) {
    gemm1_kernel<<<dim3(H_ / 128, NTOK / 128), 256, 0, stream>>>(xbf, W1T, W3T, counts, lists,
                                                                 gates, hbuf, e);
    gemm2_kernel<<<dim3(D_ / 128, NTOK / 128), 256, 0, stream>>>(hbuf, W2T, counts, lists, y, e);
  }
  finalize_kernel<<<1, 256, 0, stream>>>(Wp, probSum, zSum, y + (size_t)NTOK * D_);
}